// Round 1
// baseline (74.457 us; speedup 1.0000x reference)
//
#include <hip/hip_runtime.h>

// Plenoxel query: per-point voxel gather + SH-basis color.
// Memory-bound; key opt vs reference = skip gather + d-load for masked-out
// points (~68% of them).

__global__ __launch_bounds__(256) void plenoxel_kernel(
    const float* __restrict__ x,
    const float* __restrict__ d,
    const float* __restrict__ vg,
    float* __restrict__ out,
    int P)
{
    const float C0   = 0.28209479177387814f;
    const float C1   = 0.4886025119029199f;
    const float C2_0 = 1.0925484305920792f;
    const float C2_1 = -1.0925484305920792f;
    const float C2_2 = 0.31539156525252005f;
    const float C2_3 = -1.0925484305920792f;
    const float C2_4 = 0.5462742152960396f;

    const int stride = gridDim.x * blockDim.x;
    for (int p = blockIdx.x * blockDim.x + threadIdx.x; p < P; p += stride) {
        const float x0 = x[3 * p + 0];
        const float x1 = x[3 * p + 1];
        const float x2 = x[3 * p + 2];
        const bool mask = (fabsf(x0) < 1.0f) & (fabsf(x1) < 1.0f) & (fabsf(x2) < 1.0f);

        float c0 = 0.f, c1 = 0.f, c2 = 0.f, sg = 0.f;
        if (mask) {
            // idx = clip((x*64 + 64).astype(int32), 0, 127); C cast truncates
            // toward zero, matching JAX astype(int32).
            int ix = (int)(x0 * 64.f + 64.f);
            int iy = (int)(x1 * 64.f + 64.f);
            int iz = (int)(x2 * 64.f + 64.f);
            ix = min(max(ix, 0), 127);
            iy = min(max(iy, 0), 127);
            iz = min(max(iz, 0), 127);

            // 28-float record, 112 B = 7x16 B -> float4 loads are aligned.
            const float4* rec =
                (const float4*)(vg + (size_t)(((ix * 128 + iy) * 128 + iz)) * 28);
            const float4 r0 = rec[0];
            const float4 r1 = rec[1];
            const float4 r2 = rec[2];
            const float4 r3 = rec[3];
            const float4 r4 = rec[4];
            const float4 r5 = rec[5];
            const float4 r6 = rec[6];

            const float dx = d[3 * p + 0];
            const float dy = d[3 * p + 1];
            const float dz = d[3 * p + 2];

            const float sh0 = C0;
            const float sh1 = -C1 * dy;
            const float sh2 = C1 * dz;
            const float sh3 = -C1 * dx;
            const float sh4 = C2_0 * dx * dy;
            const float sh5 = C2_1 * dy * dz;
            const float sh6 = C2_2 * (2.f * dz * dz - dx * dx - dy * dy);
            const float sh7 = C2_3 * dx * dz;
            const float sh8 = C2_4 * (dx * dx - dy * dy);

            sg = fmaxf(r0.x, 0.f);  // relu(tmp[0])

            // k[c][j] = tmp[1 + 9c + j]
            c0 = r0.y * sh0 + r0.z * sh1 + r0.w * sh2 + r1.x * sh3 + r1.y * sh4 +
                 r1.z * sh5 + r1.w * sh6 + r2.x * sh7 + r2.y * sh8;
            c1 = r2.z * sh0 + r2.w * sh1 + r3.x * sh2 + r3.y * sh3 + r3.z * sh4 +
                 r3.w * sh5 + r4.x * sh6 + r4.y * sh7 + r4.z * sh8;
            c2 = r4.w * sh0 + r5.x * sh1 + r5.y * sh2 + r5.z * sh3 + r5.w * sh4 +
                 r6.x * sh5 + r6.y * sh6 + r6.z * sh7 + r6.w * sh8;
        }

        out[3 * p + 0] = c0;
        out[3 * p + 1] = c1;
        out[3 * p + 2] = c2;
        out[(size_t)3 * P + p] = sg;
    }
}

extern "C" void kernel_launch(void* const* d_in, const int* in_sizes, int n_in,
                              void* d_out, int out_size, void* d_ws, size_t ws_size,
                              hipStream_t stream) {
    const float* x  = (const float*)d_in[0];
    const float* d  = (const float*)d_in[1];
    const float* vg = (const float*)d_in[2];
    float* out = (float*)d_out;
    const int P = in_sizes[0] / 3;

    const int block = 256;
    const int grid = 2048;  // 8 blocks/CU on 256 CUs -> full occupancy, grid-stride x8
    plenoxel_kernel<<<grid, block, 0, stream>>>(x, d, vg, out, P);
}